// Round 4
// baseline (363.485 us; speedup 1.0000x reference)
//
#include <hip/hip_runtime.h>

#define BATCH   32
#define DIM     128
#define NBASES  8
#define SSTEPS  128
#define MAT     (DIM*DIM)
#define NELEM   (BATCH*MAT)

// ---- all scratch in device globals (.bss, ~22 MB): no d_ws, no ws_size risk ----
__device__ __align__(16) float g_X [NELEM];
__device__ __align__(16) float g_X2[NELEM];
__device__ __align__(16) float g_X3[NELEM];
__device__ __align__(16) float g_X4[NELEM];
__device__ __align__(16) float g_c0[NELEM];
__device__ __align__(16) float g_c1[NELEM];
__device__ __align__(16) float g_c2[NELEM];
__device__ __align__(16) float g_rs[NELEM];
__device__ __align__(16) float g_ks[NELEM];
__device__ __align__(16) float g_U [BATCH * 2 * SSTEPS * DIM];   // doubling history (4 MB)

__device__ __forceinline__ float* chsel(int i) {
    i %= 3; return i == 0 ? g_c0 : (i == 1 ? g_c1 : g_c2);
}

// ================= generic 16-row panel matmul (f32) =================
// One block: 16 rows x 128 cols of one batch matrix.
// thread t: rows rbase..rbase+3 (tr = t>>6 wave-uniform -> A loads broadcast),
//           cols tc*2, tc*2+1 (float2 B loads, coalesced).
// MODE 0: O = A@B
// MODE 1: O = (fa0*I+fa1*X+fa2*X2+fa3*X3)@B * scale + (ea0*I+ea1*X+ea2*X2+ea3*X3)
// MODE 2: O = A@B * scale + (ea-poly)
// MODE 3: MODE 2 with transposed store (chain ends up holding M^T)
template<int MODE>
__device__ __forceinline__ void mm_panel(
    const float* __restrict__ A, const float* __restrict__ Bm, float* __restrict__ O,
    const float* __restrict__ Xb, const float* __restrict__ X2b, const float* __restrict__ X3b,
    float fa0, float fa1, float fa2, float fa3,
    float ea0, float ea1, float ea2, float ea3,
    float scale, int r0, int t)
{
    const int tr = t >> 6, tc = t & 63;
    const int rbase = r0 + tr * 4;
    float ax[4] = {0.f, 0.f, 0.f, 0.f};
    float ay[4] = {0.f, 0.f, 0.f, 0.f};
    for (int k = 0; k < DIM; ++k) {
        const float2 bv = *reinterpret_cast<const float2*>(Bm + k * DIM + tc * 2);
        #pragma unroll
        for (int i = 0; i < 4; ++i) {
            const int r = rbase + i;
            float a;
            if (MODE == 1) {
                a = fa1 * Xb[r * DIM + k] + fa2 * X2b[r * DIM + k] + fa3 * X3b[r * DIM + k];
                if (k == r) a += fa0;
            } else {
                a = A[r * DIM + k];
            }
            ax[i] += a * bv.x;
            ay[i] += a * bv.y;
        }
    }
    #pragma unroll
    for (int i = 0; i < 4; ++i) {
        const int r = rbase + i;
        const int jx = tc * 2, jy = jx + 1;
        float vx = ax[i], vy = ay[i];
        if (MODE >= 1) {
            vx = vx * scale + ea1 * Xb[r * DIM + jx] + ea2 * X2b[r * DIM + jx] + ea3 * X3b[r * DIM + jx];
            vy = vy * scale + ea1 * Xb[r * DIM + jy] + ea2 * X2b[r * DIM + jy] + ea3 * X3b[r * DIM + jy];
            if (r == jx) vx += ea0;
            if (r == jy) vy += ea0;
        }
        if (MODE == 3) { O[jx * DIM + r] = vx; O[jy * DIM + r] = vy; }
        else           { O[r * DIM + jx] = vx; O[r * DIM + jy] = vy; }
    }
}

// ================= kernels =================

__global__ __launch_bounds__(256)
void k_sums(const float* __restrict__ kco, const float* __restrict__ rco,
            const float* __restrict__ KB,  const float* __restrict__ RB)
{
    const int blk = blockIdx.x, t = threadIdx.x;
    const int b = blk >> 3, r0 = (blk & 7) * 16;
    float rc[NBASES], kc[NBASES];
    #pragma unroll
    for (int n = 0; n < NBASES; ++n) { rc[n] = rco[b * NBASES + n]; kc[n] = kco[b * NBASES + n]; }
    const int row = r0 + (t >> 4), j0 = (t & 15) * 8;
    #pragma unroll
    for (int jj = 0; jj < 8; ++jj) {
        const int j = j0 + jj;
        float rs = 0.f, ks = 0.f;
        #pragma unroll
        for (int n = 0; n < NBASES; ++n) {
            rs += rc[n] * RB[n * MAT + row * DIM + j];
            ks += kc[n] * KB[n * MAT + row * DIM + j];
        }
        g_rs[b * MAT + row * DIM + j] = rs;
        g_ks[b * MAT + row * DIM + j] = ks;
    }
}

// X = (alpha*skew(Ksum) - beta*(Rsum^T@Rsum)) * dt + 1e-6*I  (f64 accum, f32 store)
__global__ __launch_bounds__(256)
void k_buildX(const float* __restrict__ alp, const float* __restrict__ bet,
              const float* __restrict__ ts)
{
    const int blk = blockIdx.x, t = threadIdx.x;
    const int b = blk >> 3, r0 = (blk & 7) * 16;
    const double alpha = (double)alp[b], beta = (double)bet[b];
    const double dt = (double)ts[0];
    const int row = r0 + (t >> 4), j0 = (t & 15) * 8;
    const float* Rb = g_rs + b * MAT;
    double acc[8] = {0, 0, 0, 0, 0, 0, 0, 0};
    for (int k = 0; k < DIM; ++k) {
        const double ri = (double)Rb[k * DIM + row];
        #pragma unroll
        for (int jj = 0; jj < 8; ++jj) acc[jj] += ri * (double)Rb[k * DIM + j0 + jj];
    }
    #pragma unroll
    for (int jj = 0; jj < 8; ++jj) {
        const int j = j0 + jj;
        const double ksym = (double)g_ks[b * MAT + row * DIM + j]
                          - (double)g_ks[b * MAT + j * DIM + row];
        double x = (alpha * ksym - beta * acc[jj]) * dt;  // beta * neg_gram
        if (row == j) x += 1e-6;
        g_X[b * MAT + row * DIM + j] = (float)x;
    }
}

__global__ __launch_bounds__(256)
void k_X2()
{
    const int b = blockIdx.x >> 3, r0 = (blockIdx.x & 7) * 16;
    mm_panel<0>(g_X + b * MAT, g_X + b * MAT, g_X2 + b * MAT, nullptr, nullptr, nullptr,
                0, 0, 0, 0, 0, 0, 0, 0, 0.f, r0, threadIdx.x);
}

__global__ __launch_bounds__(256)
void k_X3X4()
{
    const int job = blockIdx.x >> 8, bl = blockIdx.x & 255;
    const int b = bl >> 3, r0 = (bl & 7) * 16;
    if (job == 0)
        mm_panel<0>(g_X + b * MAT, g_X2 + b * MAT, g_X3 + b * MAT, nullptr, nullptr, nullptr,
                    0, 0, 0, 0, 0, 0, 0, 0, 0.f, r0, threadIdx.x);
    else
        mm_panel<0>(g_X2 + b * MAT, g_X2 + b * MAT, g_X4 + b * MAT, nullptr, nullptr, nullptr,
                    0, 0, 0, 0, 0, 0, 0, 0, 0.f, r0, threadIdx.x);
}

// Degree-15 Taylor of exp(T), T = X/4 (fixed s=2), Paterson-Stockmeyer groups of 4.
#define UU  0.25
#define UU2 (UU*UU)
#define UU3 (UU2*UU)
#define UU4 (UU2*UU2)

__global__ __launch_bounds__(256)
void k_H1()   // H1 = B3@T4 + B2 -> c1
{
    const int b = blockIdx.x >> 3, r0 = (blockIdx.x & 7) * 16;
    mm_panel<1>(nullptr, g_X4 + b * MAT, g_c1 + b * MAT,
                g_X + b * MAT, g_X2 + b * MAT, g_X3 + b * MAT,
                (float)(1.0 / 479001600.0), (float)(UU / 6227020800.0),
                (float)(UU2 / 87178291200.0), (float)(UU3 / 1307674368000.0),
                (float)(1.0 / 40320.0), (float)(UU / 362880.0),
                (float)(UU2 / 3628800.0), (float)(UU3 / 39916800.0),
                (float)UU4, r0, threadIdx.x);
}

__global__ __launch_bounds__(256)
void k_H2()   // H2 = H1@T4 + B1 -> c2
{
    const int b = blockIdx.x >> 3, r0 = (blockIdx.x & 7) * 16;
    mm_panel<2>(g_c1 + b * MAT, g_X4 + b * MAT, g_c2 + b * MAT,
                g_X + b * MAT, g_X2 + b * MAT, g_X3 + b * MAT,
                0, 0, 0, 0,
                (float)(1.0 / 24.0), (float)(UU / 120.0),
                (float)(UU2 / 720.0), (float)(UU3 / 5040.0),
                (float)UU4, r0, threadIdx.x);
}

__global__ __launch_bounds__(256)
void k_H3()   // H3 = H2@T4 + B0 -> c0, transposed store (c0 = exp(T)^T)
{
    const int b = blockIdx.x >> 3, r0 = (blockIdx.x & 7) * 16;
    mm_panel<3>(g_c2 + b * MAT, g_X4 + b * MAT, g_c0 + b * MAT,
                g_X + b * MAT, g_X2 + b * MAT, g_X3 + b * MAT,
                0, 0, 0, 0,
                1.0f, (float)UU, (float)(UU2 * 0.5), (float)(UU3 / 6.0),
                (float)UU4, r0, threadIdx.x);
}

// chain squaring: C_dst = C_src^2 (transposed chain closed under squaring)
__global__ __launch_bounds__(256)
void k_sq(int srci, int dsti)
{
    const int b = blockIdx.x >> 3, r0 = (blockIdx.x & 7) * 16;
    const float* src = chsel(srci) + b * MAT;
    mm_panel<0>(src, src, chsel(dsti) + b * MAT, nullptr, nullptr, nullptr,
                0, 0, 0, 0, 0, 0, 0, 0, 0.f, r0, threadIdx.x);
}

// ---------------- stage-doubling mat-vec ----------------
// W stored transposed: W[i*128+o] = M^(2^k)[o,i]; u_new[o] = sum_i M[o,i]*u[i].
// History lives in g_U; slot s holds u_{s+1}. two_k==0: source z0, writes slot 0.
// Output writes are bounds-checked against out_size; layout chosen by `interleaved`.
template<int G>
__device__ __forceinline__ void matvec_stage(
    const float* __restrict__ z0r, const float* __restrict__ z0i, float* __restrict__ outF,
    const float* __restrict__ W, int bb, int c, int jbase, int two_k, int t,
    float* __restrict__ uold, int interleaved, int out_size)
{
    constexpr int HG = (G + 1) / 2;
    for (int idx = t; idx < G * DIM; idx += 256) {
        const int v = idx >> 7, i = idx & 127;
        float val;
        if (two_k == 0) val = c ? z0i[bb * DIM + i] : z0r[bb * DIM + i];
        else            val = g_U[(((bb << 1) + c) * SSTEPS + (jbase + v)) * DIM + i];
        uold[v * DIM + i] = val;
    }
    __syncthreads();
    const int o = t & 127, vh = t >> 7;
    const int vstart = vh * HG;
    if (vstart < G) {
        float acc[HG];
        #pragma unroll
        for (int v = 0; v < HG; ++v) acc[v] = 0.f;
        for (int i = 0; i < DIM; ++i) {
            const float wv = W[i * DIM + o];
            #pragma unroll
            for (int v = 0; v < HG; ++v) acc[v] += wv * uold[(vstart + v) * DIM + i];
        }
        #pragma unroll
        for (int v = 0; v < HG; ++v) {
            const int sidx = (two_k == 0) ? 0 : (jbase + vstart + v + two_k);
            const float val = acc[v];
            g_U[(((bb << 1) + c) * SSTEPS + sidx) * DIM + o] = val;
            if (interleaved) {
                const int oi = (((bb * SSTEPS) + sidx) * DIM + o) * 2 + c;
                if (oi < out_size) outF[oi] = val;
            } else if (c == 0) {
                const int oi = ((bb * SSTEPS) + sidx) * DIM + o;
                if (oi < out_size) outF[oi] = val;
            }
        }
    }
}

// One doubling window: blocks [0,mv_base) square the chain, the rest run mat-vecs.
template<int G>
__global__ __launch_bounds__(256)
void k_window(int sqs, int sqd, int wi,
              const float* __restrict__ z0r, const float* __restrict__ z0i,
              float* __restrict__ outF,
              int two_k, int ngroups, int mv_base, int interleaved, int out_size)
{
    __shared__ float uold[16 * DIM];
    const int blk = blockIdx.x, t = threadIdx.x;
    if (blk < mv_base) {
        const int b = blk >> 3, r0 = (blk & 7) * 16;
        const float* src = chsel(sqs) + b * MAT;
        mm_panel<0>(src, src, chsel(sqd) + b * MAT, nullptr, nullptr, nullptr,
                    0, 0, 0, 0, 0, 0, 0, 0, 0.f, r0, t);
    } else {
        const int m = blk - mv_base;
        const int per = 2 * ngroups;
        const int bb = m / per, rem = m % per;
        const int c = rem / ngroups, grp = rem % ngroups;
        matvec_stage<G>(z0r, z0i, outF, chsel(wi) + bb * MAT, bb, c, grp * G, two_k, t,
                        uold, interleaved, out_size);
    }
}

// ================= host =================
extern "C" void kernel_launch(void* const* d_in, const int* in_sizes, int n_in,
                              void* d_out, int out_size, void* d_ws, size_t ws_size,
                              hipStream_t stream)
{
    (void)in_sizes; (void)n_in; (void)d_ws; (void)ws_size;
    const float* z0r = (const float*)d_in[0];
    const float* z0i = (const float*)d_in[1];
    const float* ts  = (const float*)d_in[2];
    const float* kco = (const float*)d_in[3];
    const float* rco = (const float*)d_in[4];
    const float* alp = (const float*)d_in[5];
    const float* bet = (const float*)d_in[6];
    const float* KB  = (const float*)d_in[7];
    const float* RB  = (const float*)d_in[8];
    float* outF = (float*)d_out;

    // complex64 output if the harness sized d_out for (re,im) pairs; else real part.
    const int interleaved = (out_size >= 2 * BATCH * SSTEPS * DIM) ? 1 : 0;

    k_sums  <<<256, 256, 0, stream>>>(kco, rco, KB, RB);
    k_buildX<<<256, 256, 0, stream>>>(alp, bet, ts);
    k_X2    <<<256, 256, 0, stream>>>();
    k_X3X4  <<<512, 256, 0, stream>>>();
    k_H1    <<<256, 256, 0, stream>>>();
    k_H2    <<<256, 256, 0, stream>>>();
    k_H3    <<<256, 256, 0, stream>>>();        // c0 = exp(T)^T
    k_sq    <<<256, 256, 0, stream>>>(0, 1);    // c1 = C_1
    k_sq    <<<256, 256, 0, stream>>>(1, 2);    // c2 = C_2 = M^T

    // 8 windows: chain squaring C_{3+w} = C_{2+w}^2 (w<=5) fused with doubling
    // mat-vecs u_{j+2^k} = M^(2^k) u_j (k = w-1; w=0 seeds u_1 = M z).
    for (int w = 0; w < 8; ++w) {
        const int sqs = (2 + w) % 3;
        const int sqd = (3 + w) % 3;
        const int wi  = (w == 0) ? 2 : ((w + 1) % 3);
        const int two_k = (w == 0) ? 0 : (1 << (w - 1));
        const int ngroups = (w >= 6) ? ((1 << (w - 1)) >> 4) : 1;  // w=6:2, w=7:4
        const int njobs = 64 * ngroups;
        const int mv_base = (w <= 5) ? 256 : 0;
        const int grid = mv_base + njobs;
        switch (w) {
            case 0:
            case 1: k_window<1> <<<grid, 256, 0, stream>>>(sqs, sqd, wi, z0r, z0i, outF, two_k, ngroups, mv_base, interleaved, out_size); break;
            case 2: k_window<2> <<<grid, 256, 0, stream>>>(sqs, sqd, wi, z0r, z0i, outF, two_k, ngroups, mv_base, interleaved, out_size); break;
            case 3: k_window<4> <<<grid, 256, 0, stream>>>(sqs, sqd, wi, z0r, z0i, outF, two_k, ngroups, mv_base, interleaved, out_size); break;
            case 4: k_window<8> <<<grid, 256, 0, stream>>>(sqs, sqd, wi, z0r, z0i, outF, two_k, ngroups, mv_base, interleaved, out_size); break;
            default:k_window<16><<<grid, 256, 0, stream>>>(sqs, sqd, wi, z0r, z0i, outF, two_k, ngroups, mv_base, interleaved, out_size); break;
        }
    }
}

// Round 5
// 266.769 us; speedup vs baseline: 1.3625x; 1.3625x over previous
//
#include <hip/hip_runtime.h>

#define BATCH   32
#define DIM     128
#define NBASES  8
#define SSTEPS  128
#define MAT     (DIM*DIM)
#define NELEM   (BATCH*MAT)

// ---- all scratch in device globals (.bss): no d_ws use, no ws_size risk ----
__device__ __align__(16) float g_X [NELEM];
__device__ __align__(16) float g_X2[NELEM];
__device__ __align__(16) float g_X3[NELEM];
__device__ __align__(16) float g_X4[NELEM];
__device__ __align__(16) float g_c0[NELEM];
__device__ __align__(16) float g_c1[NELEM];
__device__ __align__(16) float g_c2[NELEM];
__device__ __align__(16) float g_rs[NELEM];
__device__ __align__(16) float g_ks[NELEM];
__device__ __align__(16) float g_U [BATCH * 2 * SSTEPS * DIM];   // doubling history

__device__ __forceinline__ float* chsel(int i) {
    i %= 3; return i == 0 ? g_c0 : (i == 1 ? g_c1 : g_c2);
}

// ================= 16-row panel matmul, 512 threads =================
// Block: 16 rows x 128 cols of one batch matrix. Thread t: rows rbase..rbase+1
// (tr = t>>6 wave-uniform -> A loads are wave-broadcast), cols 2tc, 2tc+1
// (float2 B loads, coalesced).
// POLYA: A(r,k) = fa0*I + fa1*X + fa2*X2 + fa3*X3  (formed on the fly)
// EPI:   O = acc*scale + (ea0*I + ea1*X + ea2*X2 + ea3*X3)
// TRANS: transposed store (O[j,r] = val) -> used once so the chain holds M^T
template<bool POLYA, bool EPI, bool TRANS>
__device__ __forceinline__ void mm_panel(
    const float* __restrict__ A, const float* __restrict__ Bm, float* __restrict__ O,
    const float* __restrict__ Xb, const float* __restrict__ X2b, const float* __restrict__ X3b,
    float fa0, float fa1, float fa2, float fa3,
    float ea0, float ea1, float ea2, float ea3,
    float scale, int r0, int t)
{
    const int tr = t >> 6, tc = t & 63;
    const int rbase = r0 + tr * 2;
    float ax[2] = {0.f, 0.f};
    float ay[2] = {0.f, 0.f};
    for (int k = 0; k < DIM; ++k) {
        const float2 bv = *reinterpret_cast<const float2*>(Bm + k * DIM + tc * 2);
        #pragma unroll
        for (int i = 0; i < 2; ++i) {
            const int r = rbase + i;
            float a;
            if (POLYA) {
                a = fa1 * Xb[r * DIM + k] + fa2 * X2b[r * DIM + k] + fa3 * X3b[r * DIM + k];
                if (k == r) a += fa0;
            } else {
                a = A[r * DIM + k];
            }
            ax[i] += a * bv.x;
            ay[i] += a * bv.y;
        }
    }
    #pragma unroll
    for (int i = 0; i < 2; ++i) {
        const int r = rbase + i;
        const int jx = tc * 2, jy = jx + 1;
        float vx = ax[i], vy = ay[i];
        if (EPI) {
            vx = vx * scale + ea1 * Xb[r * DIM + jx] + ea2 * X2b[r * DIM + jx] + ea3 * X3b[r * DIM + jx];
            vy = vy * scale + ea1 * Xb[r * DIM + jy] + ea2 * X2b[r * DIM + jy] + ea3 * X3b[r * DIM + jy];
            if (r == jx) vx += ea0;
            if (r == jy) vy += ea0;
        }
        if (TRANS) { O[jx * DIM + r] = vx; O[jy * DIM + r] = vy; }
        else       { O[r * DIM + jx] = vx; O[r * DIM + jy] = vy; }
    }
}

// ================= kernels =================

// Rsum/Ksum basis contractions (f32, float4-vectorized). 256 blocks x 512.
__global__ __launch_bounds__(512)
void k_sums(const float* __restrict__ kco, const float* __restrict__ rco,
            const float* __restrict__ KB,  const float* __restrict__ RB)
{
    const int blk = blockIdx.x, t = threadIdx.x;
    const int b = blk >> 3, r0 = (blk & 7) * 16;
    float rc[NBASES], kc[NBASES];
    #pragma unroll
    for (int n = 0; n < NBASES; ++n) { rc[n] = rco[b * NBASES + n]; kc[n] = kco[b * NBASES + n]; }
    const int row = r0 + (t >> 5), j0 = (t & 31) * 4;
    float4 rs = {0.f, 0.f, 0.f, 0.f}, ks = {0.f, 0.f, 0.f, 0.f};
    #pragma unroll
    for (int n = 0; n < NBASES; ++n) {
        const float4 rv = *reinterpret_cast<const float4*>(RB + n * MAT + row * DIM + j0);
        const float4 kv = *reinterpret_cast<const float4*>(KB + n * MAT + row * DIM + j0);
        rs.x += rc[n] * rv.x; rs.y += rc[n] * rv.y; rs.z += rc[n] * rv.z; rs.w += rc[n] * rv.w;
        ks.x += kc[n] * kv.x; ks.y += kc[n] * kv.y; ks.z += kc[n] * kv.z; ks.w += kc[n] * kv.w;
    }
    *reinterpret_cast<float4*>(g_rs + b * MAT + row * DIM + j0) = rs;
    *reinterpret_cast<float4*>(g_ks + b * MAT + row * DIM + j0) = ks;
}

// X = (alpha*skew(Ksum) - beta*(Rsum^T@Rsum)) * dt + 1e-6*I
// Gram as matmul: gram[r,j] = sum_k Rsum[k,r]*Rsum[k,j]
//   (A-operand Rsum[k,r]: wave-broadcast scalar loads; B float2 coalesced). f32,
//   matching the reference (_build_generator runs in f32; only expm is f64).
__global__ __launch_bounds__(512)
void k_buildX(const float* __restrict__ alp, const float* __restrict__ bet,
              const float* __restrict__ ts)
{
    const int blk = blockIdx.x, t = threadIdx.x;
    const int b = blk >> 3, r0 = (blk & 7) * 16;
    const float alpha = alp[b], beta = bet[b];
    const double dt = (double)ts[0];
    const int tr = t >> 6, tc = t & 63;
    const int rbase = r0 + tr * 2;
    const float* Rb = g_rs + b * MAT;
    const float* Kb = g_ks + b * MAT;
    float gx[2] = {0.f, 0.f}, gy[2] = {0.f, 0.f};
    for (int k = 0; k < DIM; ++k) {
        const float2 bv = *reinterpret_cast<const float2*>(Rb + k * DIM + tc * 2);
        #pragma unroll
        for (int i = 0; i < 2; ++i) {
            const float a = Rb[k * DIM + rbase + i];
            gx[i] += a * bv.x;
            gy[i] += a * bv.y;
        }
    }
    #pragma unroll
    for (int i = 0; i < 2; ++i) {
        const int r = rbase + i;
        const int jx = tc * 2, jy = jx + 1;
        const float2 krj = *reinterpret_cast<const float2*>(Kb + r * DIM + jx);
        const float ksx = krj.x - Kb[jx * DIM + r];
        const float ksy = krj.y - Kb[jy * DIM + r];
        const float axv = alpha * ksx - beta * gx[i];  // beta * neg_gram
        const float ayv = alpha * ksy - beta * gy[i];
        double xv = (double)axv * dt; if (r == jx) xv += 1e-6;
        double yv = (double)ayv * dt; if (r == jy) yv += 1e-6;
        g_X[b * MAT + r * DIM + jx] = (float)xv;
        g_X[b * MAT + r * DIM + jy] = (float)yv;
    }
}

__global__ __launch_bounds__(512)
void k_X2()
{
    const int b = blockIdx.x >> 3, r0 = (blockIdx.x & 7) * 16;
    mm_panel<false,false,false>(g_X + b * MAT, g_X + b * MAT, g_X2 + b * MAT,
                                nullptr, nullptr, nullptr,
                                0, 0, 0, 0, 0, 0, 0, 0, 0.f, r0, threadIdx.x);
}

__global__ __launch_bounds__(512)
void k_X3X4()
{
    const int job = blockIdx.x >> 8, bl = blockIdx.x & 255;
    const int b = bl >> 3, r0 = (bl & 7) * 16;
    if (job == 0)
        mm_panel<false,false,false>(g_X + b * MAT, g_X2 + b * MAT, g_X3 + b * MAT,
                                    nullptr, nullptr, nullptr,
                                    0, 0, 0, 0, 0, 0, 0, 0, 0.f, r0, threadIdx.x);
    else
        mm_panel<false,false,false>(g_X2 + b * MAT, g_X2 + b * MAT, g_X4 + b * MAT,
                                    nullptr, nullptr, nullptr,
                                    0, 0, 0, 0, 0, 0, 0, 0, 0.f, r0, threadIdx.x);
}

// Degree-7 Taylor, s=0 (||X||inf ~ 0.15 -> remainder ||X||^8/8! ~ 2e-9 << f32 eps):
// exp(X) = B0 + B1@X4,  B1 = I/24 + X/120 + X2/720 + X3/5040,
//                       B0 = I + X + X2/2 + X3/6.
// Transposed store -> c0 = exp(X)^T = M^T in one matmul.
__global__ __launch_bounds__(512)
void k_H()
{
    const int b = blockIdx.x >> 3, r0 = (blockIdx.x & 7) * 16;
    mm_panel<true,true,true>(nullptr, g_X4 + b * MAT, g_c0 + b * MAT,
                             g_X + b * MAT, g_X2 + b * MAT, g_X3 + b * MAT,
                             1.f/24.f, 1.f/120.f, 1.f/720.f, 1.f/5040.f,
                             1.f, 1.f, 0.5f, 1.f/6.f,
                             1.f, r0, threadIdx.x);
}

// ---------------- stage-doubling mat-vec (512 threads) ----------------
// W stored transposed: W[i*128+o] = M^(2^k)[o,i]; u_new[o] = sum_i M[o,i]*u[i].
// History in g_U; slot s holds u_{s+1}. two_k==0: source z0, writes slot 0.
// 512 threads = 4 lane-quarters of 128 output lanes, each handling HG vectors.
template<int G>
__device__ __forceinline__ void matvec_stage(
    const float* __restrict__ z0r, const float* __restrict__ z0i, float* __restrict__ outF,
    const float* __restrict__ W, int bb, int c, int jbase, int two_k, int t,
    float* __restrict__ uold, int interleaved, int out_size)
{
    constexpr int HG = (G + 3) / 4;
    for (int idx = t; idx < G * DIM; idx += 512) {
        const int v = idx >> 7, i = idx & 127;
        float val;
        if (two_k == 0) val = c ? z0i[bb * DIM + i] : z0r[bb * DIM + i];
        else            val = g_U[(((bb << 1) + c) * SSTEPS + (jbase + v)) * DIM + i];
        uold[v * DIM + i] = val;
    }
    __syncthreads();
    const int o = t & 127, vh = t >> 7;
    const int vstart = vh * HG;
    if (vstart < G) {
        float acc[HG];
        #pragma unroll
        for (int v = 0; v < HG; ++v) acc[v] = 0.f;
        for (int i = 0; i < DIM; ++i) {
            const float wv = W[i * DIM + o];        // coalesced over lanes
            #pragma unroll
            for (int v = 0; v < HG; ++v) acc[v] += wv * uold[(vstart + v) * DIM + i];  // LDS broadcast
        }
        #pragma unroll
        for (int v = 0; v < HG; ++v) {
            if (vstart + v >= G) break;
            const int sidx = (two_k == 0) ? 0 : (jbase + vstart + v + two_k);
            const float val = acc[v];
            g_U[(((bb << 1) + c) * SSTEPS + sidx) * DIM + o] = val;
            if (interleaved) {
                const int oi = (((bb * SSTEPS) + sidx) * DIM + o) * 2 + c;
                if (oi < out_size) outF[oi] = val;
            } else if (c == 0) {
                const int oi = ((bb * SSTEPS) + sidx) * DIM + o;
                if (oi < out_size) outF[oi] = val;
            }
        }
    }
}

// One doubling window: blocks [0,mv_base) square the chain (c_{w+1} = c_w^2),
// blocks [mv_base, ...) run mat-vecs u_{j+2^k} = M^(2^k) u_j with W = c_{w-1}.
template<int G>
__global__ __launch_bounds__(512)
void k_window(int sqs, int sqd, int wi,
              const float* __restrict__ z0r, const float* __restrict__ z0i,
              float* __restrict__ outF,
              int two_k, int ngroups, int mv_base, int interleaved, int out_size)
{
    __shared__ float uold[16 * DIM];
    const int blk = blockIdx.x, t = threadIdx.x;
    if (blk < mv_base) {
        const int b = blk >> 3, r0 = (blk & 7) * 16;
        const float* src = chsel(sqs) + b * MAT;
        mm_panel<false,false,false>(src, src, chsel(sqd) + b * MAT,
                                    nullptr, nullptr, nullptr,
                                    0, 0, 0, 0, 0, 0, 0, 0, 0.f, r0, t);
    } else {
        const int m = blk - mv_base;
        const int per = 2 * ngroups;
        const int bb = m / per, rem = m % per;
        const int c = rem / ngroups, grp = rem % ngroups;
        matvec_stage<G>(z0r, z0i, outF, chsel(wi) + bb * MAT, bb, c, grp * G, two_k, t,
                        uold, interleaved, out_size);
    }
}

// ================= host =================
extern "C" void kernel_launch(void* const* d_in, const int* in_sizes, int n_in,
                              void* d_out, int out_size, void* d_ws, size_t ws_size,
                              hipStream_t stream)
{
    (void)in_sizes; (void)n_in; (void)d_ws; (void)ws_size;
    const float* z0r = (const float*)d_in[0];
    const float* z0i = (const float*)d_in[1];
    const float* ts  = (const float*)d_in[2];
    const float* kco = (const float*)d_in[3];
    const float* rco = (const float*)d_in[4];
    const float* alp = (const float*)d_in[5];
    const float* bet = (const float*)d_in[6];
    const float* KB  = (const float*)d_in[7];
    const float* RB  = (const float*)d_in[8];
    float* outF = (float*)d_out;

    const int interleaved = (out_size >= 2 * BATCH * SSTEPS * DIM) ? 1 : 0;

    k_sums  <<<256, 512, 0, stream>>>(kco, rco, KB, RB);
    k_buildX<<<256, 512, 0, stream>>>(alp, bet, ts);
    k_X2    <<<256, 512, 0, stream>>>();
    k_X3X4  <<<512, 512, 0, stream>>>();
    k_H     <<<256, 512, 0, stream>>>();   // c0 = M^T directly (s=0, one Horner mm)

    // 8 windows: chain squaring c_{w+1} = c_w^2 (w<=5 -> produces c1..c6) fused
    // with doubling mat-vecs (k = w-1; w=0 seeds u_1 = M z from c0).
    for (int w = 0; w < 8; ++w) {
        const int sqs = w % 3;
        const int sqd = (w + 1) % 3;
        const int wi  = (w == 0) ? 0 : ((w - 1) % 3);
        const int two_k = (w == 0) ? 0 : (1 << (w - 1));
        const int ngroups = (w >= 6) ? ((1 << (w - 1)) >> 4) : 1;  // w=6:2, w=7:4
        const int njobs = 64 * ngroups;
        const int mv_base = (w <= 5) ? 256 : 0;
        const int grid = mv_base + njobs;
        switch (w) {
            case 0:
            case 1: k_window<1> <<<grid, 512, 0, stream>>>(sqs, sqd, wi, z0r, z0i, outF, two_k, ngroups, mv_base, interleaved, out_size); break;
            case 2: k_window<2> <<<grid, 512, 0, stream>>>(sqs, sqd, wi, z0r, z0i, outF, two_k, ngroups, mv_base, interleaved, out_size); break;
            case 3: k_window<4> <<<grid, 512, 0, stream>>>(sqs, sqd, wi, z0r, z0i, outF, two_k, ngroups, mv_base, interleaved, out_size); break;
            case 4: k_window<8> <<<grid, 512, 0, stream>>>(sqs, sqd, wi, z0r, z0i, outF, two_k, ngroups, mv_base, interleaved, out_size); break;
            default:k_window<16><<<grid, 512, 0, stream>>>(sqs, sqd, wi, z0r, z0i, outF, two_k, ngroups, mv_base, interleaved, out_size); break;
        }
    }
}